// Round 2
// baseline (1847.456 us; speedup 1.0000x reference)
//
#include <hip/hip_runtime.h>
#include <hip/hip_bf16.h>

// ---------------------------------------------------------------------------
// DEQ layer, MI355X round 6.
//  - gram: reverted to round-4 form (84 VGPR, row-coalesced atomics, 640
//    blocks). Round-5 pair-symmetric variant regressed: VGPR 256 -> 9%
//    occupancy, transposed mirror atomics 3.7x write amplification.
//  - power chain: 21 pmv launches + sigma + wfold fused into ONE kernel
//    using a software grid barrier (192 blocks <= 256 CUs, co-resident;
//    device-scope atomics + threadfence, cooperative-groups pattern).
//  - GEMMs: bf16 MFMA 16x16x32, gemm1 64x64 (512 blk), gemm2 32x32 (512 blk).
//  - Anderson: wave-per-row, in-register 5x5 solve (verified prior rounds).
// ---------------------------------------------------------------------------

#define B_ROWS 2048
#define D_LAT  256
#define D_CTX  256
#define D_HID  1024
#define KCAT   512
#define SLOT   (B_ROWS * D_LAT)
#define NRING  7

typedef __bf16 bf16x8 __attribute__((ext_vector_type(8)));
typedef float f32x4 __attribute__((ext_vector_type(4)));
typedef unsigned short u16;

// ---------------- init: zc = [bf16(0)|bf16(ctx)], uA=1, vA=0, G=0, bar=0 ---
__global__ void init_kernel(const float* __restrict__ ctx,
                            __hip_bfloat16* __restrict__ zc,
                            float* __restrict__ vA, float* __restrict__ uA,
                            float* __restrict__ G1p, float* __restrict__ G2,
                            int* __restrict__ bar) {
  int i = blockIdx.x * 256 + threadIdx.x;
  if (i < B_ROWS * KCAT) {
    int b = i >> 9, c = i & 511;
    float v = (c < 256) ? 0.0f : ctx[b * 256 + (c - 256)];
    zc[i] = __float2bfloat16(v);
  }
  if (i < 512 * 512) G1p[i] = 0.0f;
  if (i < 256 * 256) G2[i] = 0.0f;
  if (i < KCAT) vA[i] = 0.0f;
  if (i < D_LAT) uA[i] = 1.0f;
  if (i < 64) bar[i] = 0;
}

// ---------------- Gram build, split-K x8, atomic accumulate (round-4) ------
// blocks 0..511:  G1' = W1^T W1  (mode A: G[i][j] = sum_k X[k*512+i]X[k*512+j])
//   tiles 8x8 of 64, splits of K=128 over W1's 1024 rows.
// blocks 512..639: G2 = W2 W2^T (mode B: G[i][j] = sum_k X[i*1024+k]X[j*1024+k])
//   tiles 4x4 of 64, splits of 128 over W2's 1024 cols.
__global__ __launch_bounds__(256) void gram_kernel(
    const float* __restrict__ W1, const float* __restrict__ W2,
    float* __restrict__ G1p, float* __restrict__ G2) {
  __shared__ float As[32][66];
  __shared__ float Bs[32][66];
  const int tid = threadIdx.x;
  const int tx = tid & 15, ty = tid >> 4;

  const float* X; float* G; int N, ti, tj, k0base; bool modeA;
  int b = blockIdx.x;
  if (b < 512) {
    modeA = true; X = W1; G = G1p; N = 512;
    int s = b >> 6, t = b & 63;
    ti = t >> 3; tj = t & 7; k0base = s * 128;
  } else {
    modeA = false; b -= 512; X = W2; G = G2; N = 256;
    int s = b >> 4, t = b & 15;
    ti = t >> 2; tj = t & 3; k0base = s * 128;
  }

  float acc[4][4] = {};
  for (int k0 = k0base; k0 < k0base + 128; k0 += 32) {
    if (modeA) {
      for (int idx = tid; idx < 2048; idx += 256) {
        int r = idx & 63, c = idx >> 6;
        As[c][r] = X[(size_t)(k0 + c) * 512 + ti * 64 + r];
        Bs[c][r] = X[(size_t)(k0 + c) * 512 + tj * 64 + r];
      }
    } else {
      for (int idx = tid; idx < 2048; idx += 256) {
        int c = idx & 31, r = idx >> 5;
        As[c][r] = X[(size_t)(ti * 64 + r) * 1024 + k0 + c];
        Bs[c][r] = X[(size_t)(tj * 64 + r) * 1024 + k0 + c];
      }
    }
    __syncthreads();
#pragma unroll
    for (int kk = 0; kk < 32; kk++) {
      const float2* ap = (const float2*)&As[kk][ty * 4];
      const float2* bp = (const float2*)&Bs[kk][tx * 4];
      float2 a0 = ap[0], a1 = ap[1];
      float2 b0 = bp[0], b1 = bp[1];
      float a[4] = {a0.x, a0.y, a1.x, a1.y};
      float bb[4] = {b0.x, b0.y, b1.x, b1.y};
#pragma unroll
      for (int i = 0; i < 4; i++)
#pragma unroll
        for (int j = 0; j < 4; j++) acc[i][j] += a[i] * bb[j];
    }
    __syncthreads();
  }
#pragma unroll
  for (int i = 0; i < 4; i++)
#pragma unroll
    for (int j = 0; j < 4; j++)
      atomicAdd(&G[(size_t)(ti * 64 + ty * 4 + i) * N + tj * 64 + tx * 4 + j],
                acc[i][j]);
}

// ---------------- colsum: vA += W1^T ones (atomic partials) ----------------
__global__ __launch_bounds__(256) void colsum_kernel(
    const float* __restrict__ W1, float* __restrict__ vA) {
  int b = blockIdx.x;  // 64 blocks, rows [16b,16b+16)
  for (int c = threadIdx.x; c < KCAT; c += 256) {
    float s = 0.f;
#pragma unroll
    for (int r = 0; r < 16; r++) s += W1[(size_t)(16 * b + r) * KCAT + c];
    atomicAdd(&vA[c], s);
  }
}

// ---------------- software grid barrier (blocks co-resident) ---------------
__device__ __forceinline__ void grid_barrier(int* bar, int slot, int nblk) {
  __syncthreads();
  if (threadIdx.x == 0) {
    __threadfence();
    int prev = __hip_atomic_fetch_add(&bar[slot], 1, __ATOMIC_ACQ_REL,
                                      __HIP_MEMORY_SCOPE_AGENT);
    if (prev + 1 < nblk) {
      long spin = 0;
      while (__hip_atomic_load(&bar[slot], __ATOMIC_ACQUIRE,
                               __HIP_MEMORY_SCOPE_AGENT) < nblk) {
        __builtin_amdgcn_s_sleep(2);
        if (++spin > (long)2e8) break;  // hang insurance; never hit normally
      }
    }
    __threadfence();
  }
  __syncthreads();
}

// ---------------- fused power chain + sigma + wfold ------------------------
// 192 blocks x 4 waves. Waves 0..511: G1' row matvecs (active it>=2);
// waves 512..767: G2 row matvecs (all 21 its). Ping-pong identical to the
// old pmv chain; then block 0 computes sigma; then all blocks fold weights.
//   final: vA=v21, vB=v20, uA=u20, uB=u21
//   1/sig1 = sqrt(0.25*(vA.vB)/(vA.vA)); 1/sig2 = sqrt(0.25*(uA.uA)/(uA.uB))
__global__ __launch_bounds__(256) void power_kernel(
    const float* __restrict__ G1p, const float* __restrict__ G2,
    float* __restrict__ vA, float* __restrict__ vB,
    float* __restrict__ uA, float* __restrict__ uB,
    float* __restrict__ sig, int* __restrict__ bar,
    const float* __restrict__ W1, const float* __restrict__ W2,
    __hip_bfloat16* __restrict__ W1b, __hip_bfloat16* __restrict__ W2b) {
  __shared__ float red[4][4];
  const int tid = threadIdx.x;
  const int lane = tid & 63, wid = tid >> 6;
  const int gw = blockIdx.x * 4 + wid;
  const bool vside = gw < 512;
  const int r = vside ? gw : gw - 512;
  const int n = vside ? 512 : 256;
  const float4* Gr =
      (const float4*)((vside ? G1p : G2) + (size_t)r * n);
  const int nblk = gridDim.x;

  for (int it = 1; it <= 21; ++it) {
    const float* in; float* out;
    if (vside) {
      if (it & 1) { in = vB; out = vA; } else { in = vA; out = vB; }
    } else {
      if (it & 1) { in = uA; out = uB; } else { in = uB; out = uA; }
    }
    if (!vside || it >= 2) {
      const float4* uv = (const float4*)in;
      float acc = 0.f;
      for (int c = lane; c < (n >> 2); c += 64) {
        float4 g = Gr[c], u = uv[c];
        acc += g.x * u.x + g.y * u.y + g.z * u.z + g.w * u.w;
      }
      for (int off = 32; off; off >>= 1) acc += __shfl_down(acc, off, 64);
      if (lane == 0) out[r] = 0.25f * acc;
    }
    grid_barrier(bar, it - 1, nblk);
  }

  if (blockIdx.x == 0) {
    float s[4] = {0.f, 0.f, 0.f, 0.f};
    for (int i = tid; i < KCAT; i += 256) {
      s[0] += vA[i] * vB[i];
      s[1] += vA[i] * vA[i];
    }
    for (int i = tid; i < D_LAT; i += 256) {
      s[2] += uA[i] * uA[i];
      s[3] += uA[i] * uB[i];
    }
    for (int k = 0; k < 4; k++) {
      float a = s[k];
      for (int off = 32; off; off >>= 1) a += __shfl_down(a, off, 64);
      if (lane == 0) red[k][wid] = a;
    }
    __syncthreads();
    if (tid == 0) {
      float d0 = red[0][0] + red[0][1] + red[0][2] + red[0][3];
      float d1 = red[1][0] + red[1][1] + red[1][2] + red[1][3];
      float d2 = red[2][0] + red[2][1] + red[2][2] + red[2][3];
      float d3 = red[3][0] + red[3][1] + red[3][2] + red[3][3];
      sig[0] = sqrtf(0.25f * d0 / d1);
      sig[1] = sqrtf(0.25f * d2 / d3);
    }
  }
  grid_barrier(bar, 21, nblk);

  const float s1 = sig[0], s2 = sig[1];
  const int stride = nblk * 256;
  for (int i = blockIdx.x * 256 + tid; i < D_HID * KCAT; i += stride)
    W1b[i] = __float2bfloat16(W1[i] * s1);
  for (int i = blockIdx.x * 256 + tid; i < D_LAT * D_HID; i += stride)
    W2b[i] = __float2bfloat16(W2[i] * s2);
}

// ---------------- warm-up fusions ------------------------------------------
// warm1: X1 = F0; zc left = bf16(F0)
__global__ void warm1_kernel(const float* __restrict__ Fh,
                             float* __restrict__ Xh,
                             __hip_bfloat16* __restrict__ zc) {
  int i = blockIdx.x * 256 + threadIdx.x;
  float v = Fh[i];
  Xh[SLOT + i] = v;
  zc[(i >> 8) * KCAT + (i & 255)] = __float2bfloat16(v);
}
// warm2: X2 = F0; F2 = F1
__global__ void warm2_kernel(const float* __restrict__ Fh,
                             float* __restrict__ Xh, float* __restrict__ Fw) {
  int i = blockIdx.x * 256 + threadIdx.x;
  Xh[2 * SLOT + i] = Fh[i];
  Fw[2 * SLOT + i] = Fh[SLOT + i];
}

// ---------------- bf16 MFMA GEMM: C = tanh(A @ W^T + bias) -----------------
template <int BM, int BN, bool OUT_BF16>
__global__ __launch_bounds__(256) void gemm_mfma(
    const __hip_bfloat16* __restrict__ A, const __hip_bfloat16* __restrict__ W,
    int K, const float* __restrict__ bias, float* __restrict__ Cf,
    __hip_bfloat16* __restrict__ Cb, int N) {
  __shared__ __align__(16) u16 lds[(BM + BN) * 64];
  u16* As = lds;
  u16* Ws = lds + BM * 64;
  const int tid = threadIdx.x;
  const int lane = tid & 63;
  const int wid = tid >> 6;
  const int wy = wid >> 1, wx = wid & 1;
  constexpr int WM = BM / 2, WN = BN / 2;
  constexpr int MB = WM / 16, NB = WN / 16;
  const int bm = blockIdx.x * BM;
  const int bn = blockIdx.y * BN;
  const int rlo = lane & 15, quad = lane >> 4;

  f32x4 acc[MB][NB] = {};

  for (int k0 = 0; k0 < K; k0 += 64) {
    for (int c = tid; c < BM * 8; c += 256) {
      int r = c >> 3, o = (c & 7) ^ (r & 7);
      __builtin_amdgcn_global_load_lds(
          (const __attribute__((address_space(1))) void*)(A + (size_t)(bm + r) * K + k0 + o * 8),
          (__attribute__((address_space(3))) void*)(As + c * 8), 16, 0, 0);
    }
    for (int c = tid; c < BN * 8; c += 256) {
      int r = c >> 3, o = (c & 7) ^ (r & 7);
      __builtin_amdgcn_global_load_lds(
          (const __attribute__((address_space(1))) void*)(W + (size_t)(bn + r) * K + k0 + o * 8),
          (__attribute__((address_space(3))) void*)(Ws + c * 8), 16, 0, 0);
    }
    __syncthreads();
#pragma unroll
    for (int kk = 0; kk < 2; kk++) {
      bf16x8 af[MB], bfr[NB];
#pragma unroll
      for (int mb = 0; mb < MB; mb++) {
        int r = wy * WM + mb * 16 + rlo;
        int o = (kk * 4 + quad) ^ (r & 7);
        af[mb] = *(const bf16x8*)(As + (r * 8 + o) * 8);
      }
#pragma unroll
      for (int nb = 0; nb < NB; nb++) {
        int r = wx * WN + nb * 16 + rlo;
        int o = (kk * 4 + quad) ^ (r & 7);
        bfr[nb] = *(const bf16x8*)(Ws + (r * 8 + o) * 8);
      }
#pragma unroll
      for (int mb = 0; mb < MB; mb++)
#pragma unroll
        for (int nb = 0; nb < NB; nb++)
          acc[mb][nb] = __builtin_amdgcn_mfma_f32_16x16x32_bf16(
              af[mb], bfr[nb], acc[mb][nb], 0, 0, 0);
    }
    __syncthreads();
  }

#pragma unroll
  for (int mb = 0; mb < MB; mb++) {
#pragma unroll
    for (int nb = 0; nb < NB; nb++) {
      int n = bn + wx * WN + nb * 16 + rlo;
      float bv = bias[n];
#pragma unroll
      for (int rg = 0; rg < 4; rg++) {
        int m = bm + wy * WM + mb * 16 + quad * 4 + rg;
        float val = tanhf(acc[mb][nb][rg] + bv);
        if constexpr (OUT_BF16) {
          Cb[(size_t)m * N + n] = __float2bfloat16(val);
        } else {
          Cf[(size_t)m * N + n] = val;
        }
      }
    }
  }
}

// ---------------- Anderson step (wave per batch row) ------------------------
__global__ __launch_bounds__(256) void anderson_step_kernel(
    const float* __restrict__ Xh, const float* __restrict__ Fh,
    float* __restrict__ Xw, __hip_bfloat16* __restrict__ zc, int t, int mk) {
  const int lane = threadIdx.x & 63;
  const int wid = threadIdx.x >> 6;
  const int b = blockIdx.x * 4 + wid;
  const int base = b * D_LAT + lane;

  float fa[4], xa[4], r[4], Fm1[4];
#pragma unroll
  for (int c = 0; c < 4; c++) {
    int sl = (t - 1) % NRING;
    fa[c] = Fh[sl * SLOT + base + 64 * c];
    xa[c] = Xh[sl * SLOT + base + 64 * c];
    r[c] = fa[c] - xa[c];
    Fm1[c] = fa[c];
  }

  float dF[5][4], dG[5][4];
  for (int i = 1; i <= mk; i++) {
    int sl = (t - 1 - i) % NRING;
#pragma unroll
    for (int c = 0; c < 4; c++) {
      float fb = Fh[sl * SLOT + base + 64 * c];
      float xb = Xh[sl * SLOT + base + 64 * c];
      dF[i - 1][c] = fa[c] - fb;
      float dx = xa[c] - xb;
      dG[i - 1][c] = dF[i - 1][c] - dx;
      fa[c] = fb;
      xa[c] = xb;
    }
  }

  float vals[20];
  int nv = 0;
  for (int i = 0; i < mk; i++)
    for (int j = i; j < mk; j++) {
      float s = 0.f;
#pragma unroll
      for (int c = 0; c < 4; c++) s += dG[i][c] * dG[j][c];
      vals[nv++] = s;
    }
  for (int i = 0; i < mk; i++) {
    float s = 0.f;
#pragma unroll
    for (int c = 0; c < 4; c++) s += dG[i][c] * r[c];
    vals[nv++] = s;
  }
  for (int off = 1; off <= 32; off <<= 1)
    for (int v = 0; v < nv; v++) vals[v] += __shfl_xor(vals[v], off, 64);

  double A[5][5], bv[5], alpha[5];
  int p = 0;
  for (int i = 0; i < mk; i++)
    for (int j = i; j < mk; j++) {
      A[i][j] = (double)vals[p];
      A[j][i] = (double)vals[p];
      p++;
    }
  for (int i = 0; i < mk; i++) A[i][i] += (double)1e-4f;
  for (int i = 0; i < mk; i++) bv[i] = (double)vals[p++];

  for (int c = 0; c < mk; c++) {
    double inv = 1.0 / A[c][c];
    for (int rr = c + 1; rr < mk; rr++) {
      double fct = A[rr][c] * inv;
      for (int cc = c; cc < mk; cc++) A[rr][cc] -= fct * A[c][cc];
      bv[rr] -= fct * bv[c];
    }
  }
  for (int i = mk - 1; i >= 0; i--) {
    double s = bv[i];
    for (int j = i + 1; j < mk; j++) s -= A[i][j] * alpha[j];
    alpha[i] = s / A[i][i];
  }

#pragma unroll
  for (int c = 0; c < 4; c++) {
    float x = Fm1[c];
    for (int i = 0; i < mk; i++) x -= dF[i][c] * (float)alpha[i];
    Xw[base + 64 * c] = x;
    if (zc != nullptr) zc[b * KCAT + lane + 64 * c] = __float2bfloat16(x);
  }
}

// ---------------- host orchestration ---------------------------------------
static void eval_f(const __hip_bfloat16* zc, const __hip_bfloat16* W1b,
                   const __hip_bfloat16* W2b, const float* b1, const float* b2,
                   __hip_bfloat16* hb, float* Fout, hipStream_t stream) {
  // 64x64 tiles -> (32,16) = 512 blocks (2 blocks/CU)
  gemm_mfma<64, 64, true><<<dim3(B_ROWS / 64, D_HID / 64), 256, 0, stream>>>(
      zc, W1b, KCAT, b1, nullptr, hb, D_HID);
  // 32x32 tiles -> (64,8) = 512 blocks
  gemm_mfma<32, 32, false><<<dim3(B_ROWS / 32, D_LAT / 32), 256, 0, stream>>>(
      hb, W2b, D_HID, b2, Fout, nullptr, D_LAT);
}

extern "C" void kernel_launch(void* const* d_in, const int* in_sizes, int n_in,
                              void* d_out, int out_size, void* d_ws,
                              size_t ws_size, hipStream_t stream) {
  const float* ctx = (const float*)d_in[0];
  const float* W1 = (const float*)d_in[1];
  const float* b1 = (const float*)d_in[2];
  const float* W2 = (const float*)d_in[3];
  const float* b2 = (const float*)d_in[4];
  float* out = (float*)d_out;

  float* ws = (float*)d_ws;
  float* sig = ws;                       // 16
  float* vA = ws + 16;                   // 512
  float* vB = vA + KCAT;                 // 512
  float* uA = vB + KCAT;                 // 256
  float* uB = uA + D_LAT;                // 256
  int* bar = (int*)(uB + D_LAT);         // 64 ints
  float* G1p = uB + D_LAT + 64;          // 512*512
  float* G2 = G1p + KCAT * KCAT;         // 256*256
  float* Xh = G2 + D_LAT * D_LAT;        // 7*SLOT
  float* Fh = Xh + NRING * SLOT;         // 7*SLOT
  __hip_bfloat16* W1b = (__hip_bfloat16*)(Fh + NRING * SLOT);  // 524288
  __hip_bfloat16* W2b = W1b + D_HID * KCAT;                    // 262144
  __hip_bfloat16* zc = W2b + D_LAT * D_HID;                    // 2048*512
  __hip_bfloat16* hb = zc + B_ROWS * KCAT;                     // 2048*1024
  // ~38.5 MB total

  // init: zc = [0|bf16(ctx)], uA = ones, vA = 0, G zeroed, barriers zeroed
  init_kernel<<<(B_ROWS * KCAT + 255) / 256, 256, 0, stream>>>(ctx, zc, vA, uA,
                                                               G1p, G2, bar);
  // Gram build + v1 = W1^T ones
  gram_kernel<<<640, 256, 0, stream>>>(W1, W2, G1p, G2);
  colsum_kernel<<<64, 256, 0, stream>>>(W1, vA);

  // fused: 21 damped power matvec iterations + sigma + weight fold
  power_kernel<<<192, 256, 0, stream>>>(G1p, G2, vA, vB, uA, uB, sig, bar, W1,
                                        W2, W1b, W2b);

  // x0 = 0 (f32 history slot 0); zc left half already bf16(0)
  hipMemsetAsync(Xh, 0, SLOT * sizeof(float), stream);

  // F0 = f(x0)
  eval_f(zc, W1b, W2b, b1, b2, hb, Fh, stream);
  // X1 = F0; zc = bf16(F0); F1 = f(X1)
  warm1_kernel<<<SLOT / 256, 256, 0, stream>>>(Fh, Xh, zc);
  eval_f(zc, W1b, W2b, b1, b2, hb, Fh + SLOT, stream);
  // X2 = F0; F2 = F1
  warm2_kernel<<<SLOT / 256, 256, 0, stream>>>(Fh, Xh, Fh);

  // Anderson loop: t = 3..25
  for (int t = 3; t <= 25; t++) {
    int mk = (t - 1 < 5) ? (t - 1) : 5;
    float* Xw = (t == 25) ? out : (Xh + (t % NRING) * SLOT);
    __hip_bfloat16* zarg = (t == 25) ? nullptr : zc;
    anderson_step_kernel<<<B_ROWS / 4, 256, 0, stream>>>(Xh, Fh, Xw, zarg, t, mk);
    if (t < 25) {
      eval_f(zc, W1b, W2b, b1, b2, hb, Fh + (t % NRING) * SLOT, stream);
    }
  }
}

// Round 3
// 1519.913 us; speedup vs baseline: 1.2155x; 1.2155x over previous
//
#include <hip/hip_runtime.h>
#include <hip/hip_bf16.h>

// ---------------------------------------------------------------------------
// DEQ layer, MI355X round 7.
//  - power chain: REVERTED to 21 pmv launches + sigma + wfold. The fused
//    grid-barrier version cost ~17 us PER BARRIER (375 us total, VALUBusy
//    0.5%) -- software grid barriers lose to launch chains on this chip.
//  - gram: 64x32 tiles (1280 blocks, 5/CU) instead of 64x64 (640, 2.5/CU).
//    Same 8-way split-K => same atomic/write traffic; half per-block work,
//    half accumulator VGPR. Attacks the measured latency-boundness
//    (VALUBusy 15%, Occ 19%).
//  - GEMMs: bf16 MFMA 16x16x32, gemm1 64x64 (512 blk), gemm2 32x32 (512 blk).
//  - Anderson: wave-per-row, in-register 5x5 solve (verified prior rounds).
// ---------------------------------------------------------------------------

#define B_ROWS 2048
#define D_LAT  256
#define D_CTX  256
#define D_HID  1024
#define KCAT   512
#define SLOT   (B_ROWS * D_LAT)
#define NRING  7

typedef __bf16 bf16x8 __attribute__((ext_vector_type(8)));
typedef float f32x4 __attribute__((ext_vector_type(4)));
typedef unsigned short u16;

// ---------------- init: zc = [bf16(0)|bf16(ctx)], uA=1, vA=0, G=0 ----------
__global__ void init_kernel(const float* __restrict__ ctx,
                            __hip_bfloat16* __restrict__ zc,
                            float* __restrict__ vA, float* __restrict__ uA,
                            float* __restrict__ G1p, float* __restrict__ G2) {
  int i = blockIdx.x * 256 + threadIdx.x;
  if (i < B_ROWS * KCAT) {
    int b = i >> 9, c = i & 511;
    float v = (c < 256) ? 0.0f : ctx[b * 256 + (c - 256)];
    zc[i] = __float2bfloat16(v);
  }
  if (i < 512 * 512) G1p[i] = 0.0f;
  if (i < 256 * 256) G2[i] = 0.0f;
  if (i < KCAT) vA[i] = 0.0f;
  if (i < D_LAT) uA[i] = 1.0f;
}

// ---------------- Gram build, split-K x8, 64x32 tiles, atomic accum --------
// blocks 0..1023:  G1' = W1^T W1 (mode A: G[i][j] = sum_k X[k*512+i]X[k*512+j])
//   tiles 64x32 (8x16 of them), 8 splits of K=128 over W1's 1024 rows.
// blocks 1024..1279: G2 = W2 W2^T (mode B: G[i][j]=sum_k X[i*1024+k]X[j*1024+k])
//   tiles 64x32 (4x8), 8 splits of 128 over W2's 1024 cols.
__global__ __launch_bounds__(256) void gram_kernel(
    const float* __restrict__ W1, const float* __restrict__ W2,
    float* __restrict__ G1p, float* __restrict__ G2) {
  __shared__ float As[32][66];
  __shared__ float Bs[32][34];
  const int tid = threadIdx.x;
  const int tx = tid & 15, ty = tid >> 4;

  const float* X; float* G; int N, ti, tj, k0base; bool modeA;
  int b = blockIdx.x;
  if (b < 1024) {
    modeA = true; X = W1; G = G1p; N = 512;
    int s = b >> 7, t = b & 127;
    ti = t >> 4; tj = t & 15; k0base = s * 128;
  } else {
    modeA = false; b -= 1024; X = W2; G = G2; N = 256;
    int s = b >> 5, t = b & 31;
    ti = t >> 3; tj = t & 7; k0base = s * 128;
  }

  float acc[4][2] = {};
  for (int k0 = k0base; k0 < k0base + 128; k0 += 32) {
    if (modeA) {
      for (int idx = tid; idx < 2048; idx += 256) {
        int r = idx & 63, c = idx >> 6;
        As[c][r] = X[(size_t)(k0 + c) * 512 + ti * 64 + r];
      }
      for (int idx = tid; idx < 1024; idx += 256) {
        int r = idx & 31, c = idx >> 5;
        Bs[c][r] = X[(size_t)(k0 + c) * 512 + tj * 32 + r];
      }
    } else {
      for (int idx = tid; idx < 2048; idx += 256) {
        int c = idx & 31, r = idx >> 5;
        As[c][r] = X[(size_t)(ti * 64 + r) * 1024 + k0 + c];
      }
      for (int idx = tid; idx < 1024; idx += 256) {
        int c = idx & 31, r = idx >> 5;
        Bs[c][r] = X[(size_t)(tj * 32 + r) * 1024 + k0 + c];
      }
    }
    __syncthreads();
#pragma unroll
    for (int kk = 0; kk < 32; kk++) {
      const float2* ap = (const float2*)&As[kk][ty * 4];
      float2 a0 = ap[0], a1 = ap[1];
      float2 b0 = *(const float2*)&Bs[kk][tx * 2];
      float a[4] = {a0.x, a0.y, a1.x, a1.y};
      float bb[2] = {b0.x, b0.y};
#pragma unroll
      for (int i = 0; i < 4; i++)
#pragma unroll
        for (int j = 0; j < 2; j++) acc[i][j] += a[i] * bb[j];
    }
    __syncthreads();
  }
#pragma unroll
  for (int i = 0; i < 4; i++)
#pragma unroll
    for (int j = 0; j < 2; j++)
      atomicAdd(&G[(size_t)(ti * 64 + ty * 4 + i) * N + tj * 32 + tx * 2 + j],
                acc[i][j]);
}

// ---------------- colsum: vA += W1^T ones (atomic partials) ----------------
__global__ __launch_bounds__(256) void colsum_kernel(
    const float* __restrict__ W1, float* __restrict__ vA) {
  int b = blockIdx.x;  // 64 blocks, rows [16b,16b+16)
  for (int c = threadIdx.x; c < KCAT; c += 256) {
    float s = 0.f;
#pragma unroll
    for (int r = 0; r < 16; r++) s += W1[(size_t)(16 * b + r) * KCAT + c];
    atomicAdd(&vA[c], s);
  }
}

// ---------------- joint power matvec: out = 0.25 * G in --------------------
// 192 blocks x 4 waves: gw 0..511 -> G1' rows (only if g1_active), 512..767 -> G2.
__global__ __launch_bounds__(256) void pmv_kernel(
    const float* __restrict__ G1p, const float* __restrict__ G2,
    const float* __restrict__ vi, float* __restrict__ vo,
    const float* __restrict__ ui, float* __restrict__ uo, int g1_active) {
  int gw = blockIdx.x * 4 + (threadIdx.x >> 6);
  int lane = threadIdx.x & 63;
  const float* G; const float* in; float* out; int n, r;
  if (gw < 512) {
    if (!g1_active) return;
    G = G1p; in = vi; out = vo; n = 512; r = gw;
  } else {
    G = G2; in = ui; out = uo; n = 256; r = gw - 512;
  }
  const float4* Gr = (const float4*)(G + (size_t)r * n);
  const float4* uv = (const float4*)in;
  float acc = 0.f;
  for (int c = lane; c < (n >> 2); c += 64) {
    float4 g = Gr[c], u = uv[c];
    acc += g.x * u.x + g.y * u.y + g.z * u.z + g.w * u.w;
  }
  for (int off = 32; off; off >>= 1) acc += __shfl_down(acc, off, 64);
  if (lane == 0) out[r] = 0.25f * acc;
}

// ---------------- sigma ----------------------------------------------------
// vA=v^21, vB=v^20 (damped), uA=u^20, uB=u^21 (damped). s=0.25 compensated:
// 1/sig1 = sqrt(s * (vB.vA)/(vA.vA)); 1/sig2 = sqrt(s * (uA.uA)/(uA.uB)).
__global__ __launch_bounds__(256) void sigma_kernel(
    const float* __restrict__ vA, const float* __restrict__ vB,
    const float* __restrict__ uA, const float* __restrict__ uB,
    float* __restrict__ sig) {
  float s[4] = {0.f, 0.f, 0.f, 0.f};
  for (int i = threadIdx.x; i < KCAT; i += 256) {
    s[0] += vA[i] * vB[i];
    s[1] += vA[i] * vA[i];
  }
  for (int i = threadIdx.x; i < D_LAT; i += 256) {
    s[2] += uA[i] * uA[i];
    s[3] += uA[i] * uB[i];
  }
  __shared__ float red[4][4];
  int lane = threadIdx.x & 63, w = threadIdx.x >> 6;
  for (int k = 0; k < 4; k++) {
    float a = s[k];
    for (int off = 32; off; off >>= 1) a += __shfl_down(a, off, 64);
    if (lane == 0) red[k][w] = a;
  }
  __syncthreads();
  if (threadIdx.x == 0) {
    float d0 = red[0][0] + red[0][1] + red[0][2] + red[0][3];
    float d1 = red[1][0] + red[1][1] + red[1][2] + red[1][3];
    float d2 = red[2][0] + red[2][1] + red[2][2] + red[2][3];
    float d3 = red[3][0] + red[3][1] + red[3][2] + red[3][3];
    sig[0] = sqrtf(0.25f * d0 / d1);
    sig[1] = sqrtf(0.25f * d2 / d3);
  }
}

// ---------------- fold sigma into bf16 weights -----------------------------
__global__ void wfold_kernel(const float* __restrict__ W1,
                             const float* __restrict__ W2,
                             const float* __restrict__ sig,
                             __hip_bfloat16* __restrict__ W1b,
                             __hip_bfloat16* __restrict__ W2b) {
  int i = blockIdx.x * 256 + threadIdx.x;
  if (i < D_HID * KCAT) W1b[i] = __float2bfloat16(W1[i] * sig[0]);
  int j = i - D_HID * KCAT;
  if (j >= 0 && j < D_LAT * D_HID) W2b[j] = __float2bfloat16(W2[j] * sig[1]);
}

// ---------------- warm-up fusions ------------------------------------------
// warm1: X1 = F0; zc left = bf16(F0)
__global__ void warm1_kernel(const float* __restrict__ Fh,
                             float* __restrict__ Xh,
                             __hip_bfloat16* __restrict__ zc) {
  int i = blockIdx.x * 256 + threadIdx.x;
  float v = Fh[i];
  Xh[SLOT + i] = v;
  zc[(i >> 8) * KCAT + (i & 255)] = __float2bfloat16(v);
}
// warm2: X2 = F0; F2 = F1
__global__ void warm2_kernel(const float* __restrict__ Fh,
                             float* __restrict__ Xh, float* __restrict__ Fw) {
  int i = blockIdx.x * 256 + threadIdx.x;
  Xh[2 * SLOT + i] = Fh[i];
  Fw[2 * SLOT + i] = Fh[SLOT + i];
}

// ---------------- bf16 MFMA GEMM: C = tanh(A @ W^T + bias) -----------------
template <int BM, int BN, bool OUT_BF16>
__global__ __launch_bounds__(256) void gemm_mfma(
    const __hip_bfloat16* __restrict__ A, const __hip_bfloat16* __restrict__ W,
    int K, const float* __restrict__ bias, float* __restrict__ Cf,
    __hip_bfloat16* __restrict__ Cb, int N) {
  __shared__ __align__(16) u16 lds[(BM + BN) * 64];
  u16* As = lds;
  u16* Ws = lds + BM * 64;
  const int tid = threadIdx.x;
  const int lane = tid & 63;
  const int wid = tid >> 6;
  const int wy = wid >> 1, wx = wid & 1;
  constexpr int WM = BM / 2, WN = BN / 2;
  constexpr int MB = WM / 16, NB = WN / 16;
  const int bm = blockIdx.x * BM;
  const int bn = blockIdx.y * BN;
  const int rlo = lane & 15, quad = lane >> 4;

  f32x4 acc[MB][NB] = {};

  for (int k0 = 0; k0 < K; k0 += 64) {
    for (int c = tid; c < BM * 8; c += 256) {
      int r = c >> 3, o = (c & 7) ^ (r & 7);
      __builtin_amdgcn_global_load_lds(
          (const __attribute__((address_space(1))) void*)(A + (size_t)(bm + r) * K + k0 + o * 8),
          (__attribute__((address_space(3))) void*)(As + c * 8), 16, 0, 0);
    }
    for (int c = tid; c < BN * 8; c += 256) {
      int r = c >> 3, o = (c & 7) ^ (r & 7);
      __builtin_amdgcn_global_load_lds(
          (const __attribute__((address_space(1))) void*)(W + (size_t)(bn + r) * K + k0 + o * 8),
          (__attribute__((address_space(3))) void*)(Ws + c * 8), 16, 0, 0);
    }
    __syncthreads();
#pragma unroll
    for (int kk = 0; kk < 2; kk++) {
      bf16x8 af[MB], bfr[NB];
#pragma unroll
      for (int mb = 0; mb < MB; mb++) {
        int r = wy * WM + mb * 16 + rlo;
        int o = (kk * 4 + quad) ^ (r & 7);
        af[mb] = *(const bf16x8*)(As + (r * 8 + o) * 8);
      }
#pragma unroll
      for (int nb = 0; nb < NB; nb++) {
        int r = wx * WN + nb * 16 + rlo;
        int o = (kk * 4 + quad) ^ (r & 7);
        bfr[nb] = *(const bf16x8*)(Ws + (r * 8 + o) * 8);
      }
#pragma unroll
      for (int mb = 0; mb < MB; mb++)
#pragma unroll
        for (int nb = 0; nb < NB; nb++)
          acc[mb][nb] = __builtin_amdgcn_mfma_f32_16x16x32_bf16(
              af[mb], bfr[nb], acc[mb][nb], 0, 0, 0);
    }
    __syncthreads();
  }

#pragma unroll
  for (int mb = 0; mb < MB; mb++) {
#pragma unroll
    for (int nb = 0; nb < NB; nb++) {
      int n = bn + wx * WN + nb * 16 + rlo;
      float bv = bias[n];
#pragma unroll
      for (int rg = 0; rg < 4; rg++) {
        int m = bm + wy * WM + mb * 16 + quad * 4 + rg;
        float val = tanhf(acc[mb][nb][rg] + bv);
        if constexpr (OUT_BF16) {
          Cb[(size_t)m * N + n] = __float2bfloat16(val);
        } else {
          Cf[(size_t)m * N + n] = val;
        }
      }
    }
  }
}

// ---------------- Anderson step (wave per batch row) ------------------------
__global__ __launch_bounds__(256) void anderson_step_kernel(
    const float* __restrict__ Xh, const float* __restrict__ Fh,
    float* __restrict__ Xw, __hip_bfloat16* __restrict__ zc, int t, int mk) {
  const int lane = threadIdx.x & 63;
  const int wid = threadIdx.x >> 6;
  const int b = blockIdx.x * 4 + wid;
  const int base = b * D_LAT + lane;

  float fa[4], xa[4], r[4], Fm1[4];
#pragma unroll
  for (int c = 0; c < 4; c++) {
    int sl = (t - 1) % NRING;
    fa[c] = Fh[sl * SLOT + base + 64 * c];
    xa[c] = Xh[sl * SLOT + base + 64 * c];
    r[c] = fa[c] - xa[c];
    Fm1[c] = fa[c];
  }

  float dF[5][4], dG[5][4];
  for (int i = 1; i <= mk; i++) {
    int sl = (t - 1 - i) % NRING;
#pragma unroll
    for (int c = 0; c < 4; c++) {
      float fb = Fh[sl * SLOT + base + 64 * c];
      float xb = Xh[sl * SLOT + base + 64 * c];
      dF[i - 1][c] = fa[c] - fb;
      float dx = xa[c] - xb;
      dG[i - 1][c] = dF[i - 1][c] - dx;
      fa[c] = fb;
      xa[c] = xb;
    }
  }

  float vals[20];
  int nv = 0;
  for (int i = 0; i < mk; i++)
    for (int j = i; j < mk; j++) {
      float s = 0.f;
#pragma unroll
      for (int c = 0; c < 4; c++) s += dG[i][c] * dG[j][c];
      vals[nv++] = s;
    }
  for (int i = 0; i < mk; i++) {
    float s = 0.f;
#pragma unroll
    for (int c = 0; c < 4; c++) s += dG[i][c] * r[c];
    vals[nv++] = s;
  }
  for (int off = 1; off <= 32; off <<= 1)
    for (int v = 0; v < nv; v++) vals[v] += __shfl_xor(vals[v], off, 64);

  double A[5][5], bv[5], alpha[5];
  int p = 0;
  for (int i = 0; i < mk; i++)
    for (int j = i; j < mk; j++) {
      A[i][j] = (double)vals[p];
      A[j][i] = (double)vals[p];
      p++;
    }
  for (int i = 0; i < mk; i++) A[i][i] += (double)1e-4f;
  for (int i = 0; i < mk; i++) bv[i] = (double)vals[p++];

  for (int c = 0; c < mk; c++) {
    double inv = 1.0 / A[c][c];
    for (int rr = c + 1; rr < mk; rr++) {
      double fct = A[rr][c] * inv;
      for (int cc = c; cc < mk; cc++) A[rr][cc] -= fct * A[c][cc];
      bv[rr] -= fct * bv[c];
    }
  }
  for (int i = mk - 1; i >= 0; i--) {
    double s = bv[i];
    for (int j = i + 1; j < mk; j++) s -= A[i][j] * alpha[j];
    alpha[i] = s / A[i][i];
  }

#pragma unroll
  for (int c = 0; c < 4; c++) {
    float x = Fm1[c];
    for (int i = 0; i < mk; i++) x -= dF[i][c] * (float)alpha[i];
    Xw[base + 64 * c] = x;
    if (zc != nullptr) zc[b * KCAT + lane + 64 * c] = __float2bfloat16(x);
  }
}

// ---------------- host orchestration ---------------------------------------
static void eval_f(const __hip_bfloat16* zc, const __hip_bfloat16* W1b,
                   const __hip_bfloat16* W2b, const float* b1, const float* b2,
                   __hip_bfloat16* hb, float* Fout, hipStream_t stream) {
  // 64x64 tiles -> (32,16) = 512 blocks (2 blocks/CU)
  gemm_mfma<64, 64, true><<<dim3(B_ROWS / 64, D_HID / 64), 256, 0, stream>>>(
      zc, W1b, KCAT, b1, nullptr, hb, D_HID);
  // 32x32 tiles -> (64,8) = 512 blocks
  gemm_mfma<32, 32, false><<<dim3(B_ROWS / 32, D_LAT / 32), 256, 0, stream>>>(
      hb, W2b, D_HID, b2, Fout, nullptr, D_LAT);
}

extern "C" void kernel_launch(void* const* d_in, const int* in_sizes, int n_in,
                              void* d_out, int out_size, void* d_ws,
                              size_t ws_size, hipStream_t stream) {
  const float* ctx = (const float*)d_in[0];
  const float* W1 = (const float*)d_in[1];
  const float* b1 = (const float*)d_in[2];
  const float* W2 = (const float*)d_in[3];
  const float* b2 = (const float*)d_in[4];
  float* out = (float*)d_out;

  float* ws = (float*)d_ws;
  float* sig = ws;                       // 16
  float* vA = ws + 16;                   // 512
  float* vB = vA + KCAT;                 // 512
  float* uA = vB + KCAT;                 // 256
  float* uB = uA + D_LAT;                // 256
  float* G1p = uB + D_LAT;               // 512*512
  float* G2 = G1p + KCAT * KCAT;         // 256*256
  float* Xh = G2 + D_LAT * D_LAT;        // 7*SLOT
  float* Fh = Xh + NRING * SLOT;         // 7*SLOT
  __hip_bfloat16* W1b = (__hip_bfloat16*)(Fh + NRING * SLOT);  // 524288
  __hip_bfloat16* W2b = W1b + D_HID * KCAT;                    // 262144
  __hip_bfloat16* zc = W2b + D_LAT * D_HID;                    // 2048*512
  __hip_bfloat16* hb = zc + B_ROWS * KCAT;                     // 2048*1024
  // ~38.5 MB total

  // init: zc = [0|bf16(ctx)], uA = ones, vA = 0, G zeroed (atomic targets)
  init_kernel<<<(B_ROWS * KCAT + 255) / 256, 256, 0, stream>>>(ctx, zc, vA, uA,
                                                               G1p, G2);
  // Gram build (64x32 tiles, 8 splits: 1024 + 256 blocks) + v1 = W1^T ones
  gram_kernel<<<1280, 256, 0, stream>>>(W1, W2, G1p, G2);
  colsum_kernel<<<64, 256, 0, stream>>>(W1, vA);

  // joint damped power chain:
  //   u-side all 21 its (u0=ones -> u21); v-side its 2..21 (v1 -> v21)
  for (int it = 1; it <= 21; it++) {
    const float* vi; float* vo;
    const float* ui; float* uo;
    if (it & 1) { vi = vB; vo = vA; ui = uA; uo = uB; }
    else        { vi = vA; vo = vB; ui = uB; uo = uA; }
    pmv_kernel<<<192, 256, 0, stream>>>(G1p, G2, vi, vo, ui, uo, it >= 2);
  }
  // final: vA=v21, vB=v20, uA=u20, uB=u21
  sigma_kernel<<<1, 256, 0, stream>>>(vA, vB, uA, uB, sig);
  wfold_kernel<<<(D_HID * KCAT + D_LAT * D_HID + 255) / 256, 256, 0, stream>>>(
      W1, W2, sig, W1b, W2b);

  // x0 = 0 (f32 history slot 0); zc left half already bf16(0)
  hipMemsetAsync(Xh, 0, SLOT * sizeof(float), stream);

  // F0 = f(x0)
  eval_f(zc, W1b, W2b, b1, b2, hb, Fh, stream);
  // X1 = F0; zc = bf16(F0); F1 = f(X1)
  warm1_kernel<<<SLOT / 256, 256, 0, stream>>>(Fh, Xh, zc);
  eval_f(zc, W1b, W2b, b1, b2, hb, Fh + SLOT, stream);
  // X2 = F0; F2 = F1
  warm2_kernel<<<SLOT / 256, 256, 0, stream>>>(Fh, Xh, Fh);

  // Anderson loop: t = 3..25
  for (int t = 3; t <= 25; t++) {
    int mk = (t - 1 < 5) ? (t - 1) : 5;
    float* Xw = (t == 25) ? out : (Xh + (t % NRING) * SLOT);
    __hip_bfloat16* zarg = (t == 25) ? nullptr : zc;
    anderson_step_kernel<<<B_ROWS / 4, 256, 0, stream>>>(Xh, Fh, Xw, zarg, t, mk);
    if (t < 25) {
      eval_f(zc, W1b, W2b, b1, b2, hb, Fh + (t % NRING) * SLOT, stream);
    }
  }
}

// Round 4
// 812.917 us; speedup vs baseline: 2.2726x; 1.8697x over previous
//
#include <hip/hip_runtime.h>
#include <hip/hip_bf16.h>

// ---------------------------------------------------------------------------
// DEQ layer, MI355X round 8.
//  - anderson_step: templated on MK (2,3,4,5) so all loops unroll and all
//    state (dF/dG/vals/A/alpha) is register-resident. Round-7 counters
//    showed VGPR=60 + WRITE_SIZE 57MB (vs 3MB useful) = scratch spill from
//    runtime-indexed arrays; 45us/dispatch x 23 = 2/3 of runtime.
//    Also f32x4 history loads (12 dwordx4/wave instead of 48 dword).
//  - gram: 64x32 tiles, 8-way split-K, 1280 blocks (round-7, verified).
//  - power chain: 21 pmv launches + sigma + wfold (launch chain beats
//    software grid barrier ~17us/rendezvous on this chip).
//  - GEMMs: bf16 MFMA 16x16x32, gemm1 64x64 (512 blk), gemm2 32x32 (512 blk).
// ---------------------------------------------------------------------------

#define B_ROWS 2048
#define D_LAT  256
#define D_CTX  256
#define D_HID  1024
#define KCAT   512
#define SLOT   (B_ROWS * D_LAT)
#define NRING  7

typedef __bf16 bf16x8 __attribute__((ext_vector_type(8)));
typedef float f32x4 __attribute__((ext_vector_type(4)));
typedef unsigned short u16;

// ---------------- init: zc = [bf16(0)|bf16(ctx)], uA=1, vA=0, G=0 ----------
__global__ void init_kernel(const float* __restrict__ ctx,
                            __hip_bfloat16* __restrict__ zc,
                            float* __restrict__ vA, float* __restrict__ uA,
                            float* __restrict__ G1p, float* __restrict__ G2) {
  int i = blockIdx.x * 256 + threadIdx.x;
  if (i < B_ROWS * KCAT) {
    int b = i >> 9, c = i & 511;
    float v = (c < 256) ? 0.0f : ctx[b * 256 + (c - 256)];
    zc[i] = __float2bfloat16(v);
  }
  if (i < 512 * 512) G1p[i] = 0.0f;
  if (i < 256 * 256) G2[i] = 0.0f;
  if (i < KCAT) vA[i] = 0.0f;
  if (i < D_LAT) uA[i] = 1.0f;
}

// ---------------- Gram build, split-K x8, 64x32 tiles, atomic accum --------
// blocks 0..1023:  G1' = W1^T W1 (mode A: G[i][j] = sum_k X[k*512+i]X[k*512+j])
// blocks 1024..1279: G2 = W2 W2^T (mode B: G[i][j]=sum_k X[i*1024+k]X[j*1024+k])
__global__ __launch_bounds__(256) void gram_kernel(
    const float* __restrict__ W1, const float* __restrict__ W2,
    float* __restrict__ G1p, float* __restrict__ G2) {
  __shared__ float As[32][66];
  __shared__ float Bs[32][34];
  const int tid = threadIdx.x;
  const int tx = tid & 15, ty = tid >> 4;

  const float* X; float* G; int N, ti, tj, k0base; bool modeA;
  int b = blockIdx.x;
  if (b < 1024) {
    modeA = true; X = W1; G = G1p; N = 512;
    int s = b >> 7, t = b & 127;
    ti = t >> 4; tj = t & 15; k0base = s * 128;
  } else {
    modeA = false; b -= 1024; X = W2; G = G2; N = 256;
    int s = b >> 5, t = b & 31;
    ti = t >> 3; tj = t & 7; k0base = s * 128;
  }

  float acc[4][2] = {};
  for (int k0 = k0base; k0 < k0base + 128; k0 += 32) {
    if (modeA) {
      for (int idx = tid; idx < 2048; idx += 256) {
        int r = idx & 63, c = idx >> 6;
        As[c][r] = X[(size_t)(k0 + c) * 512 + ti * 64 + r];
      }
      for (int idx = tid; idx < 1024; idx += 256) {
        int r = idx & 31, c = idx >> 5;
        Bs[c][r] = X[(size_t)(k0 + c) * 512 + tj * 32 + r];
      }
    } else {
      for (int idx = tid; idx < 2048; idx += 256) {
        int c = idx & 31, r = idx >> 5;
        As[c][r] = X[(size_t)(ti * 64 + r) * 1024 + k0 + c];
      }
      for (int idx = tid; idx < 1024; idx += 256) {
        int c = idx & 31, r = idx >> 5;
        Bs[c][r] = X[(size_t)(tj * 32 + r) * 1024 + k0 + c];
      }
    }
    __syncthreads();
#pragma unroll
    for (int kk = 0; kk < 32; kk++) {
      const float2* ap = (const float2*)&As[kk][ty * 4];
      float2 a0 = ap[0], a1 = ap[1];
      float2 b0 = *(const float2*)&Bs[kk][tx * 2];
      float a[4] = {a0.x, a0.y, a1.x, a1.y};
      float bb[2] = {b0.x, b0.y};
#pragma unroll
      for (int i = 0; i < 4; i++)
#pragma unroll
        for (int j = 0; j < 2; j++) acc[i][j] += a[i] * bb[j];
    }
    __syncthreads();
  }
#pragma unroll
  for (int i = 0; i < 4; i++)
#pragma unroll
    for (int j = 0; j < 2; j++)
      atomicAdd(&G[(size_t)(ti * 64 + ty * 4 + i) * N + tj * 32 + tx * 2 + j],
                acc[i][j]);
}

// ---------------- colsum: vA += W1^T ones (atomic partials) ----------------
__global__ __launch_bounds__(256) void colsum_kernel(
    const float* __restrict__ W1, float* __restrict__ vA) {
  int b = blockIdx.x;  // 64 blocks, rows [16b,16b+16)
  for (int c = threadIdx.x; c < KCAT; c += 256) {
    float s = 0.f;
#pragma unroll
    for (int r = 0; r < 16; r++) s += W1[(size_t)(16 * b + r) * KCAT + c];
    atomicAdd(&vA[c], s);
  }
}

// ---------------- joint power matvec: out = 0.25 * G in --------------------
__global__ __launch_bounds__(256) void pmv_kernel(
    const float* __restrict__ G1p, const float* __restrict__ G2,
    const float* __restrict__ vi, float* __restrict__ vo,
    const float* __restrict__ ui, float* __restrict__ uo, int g1_active) {
  int gw = blockIdx.x * 4 + (threadIdx.x >> 6);
  int lane = threadIdx.x & 63;
  const float* G; const float* in; float* out; int n, r;
  if (gw < 512) {
    if (!g1_active) return;
    G = G1p; in = vi; out = vo; n = 512; r = gw;
  } else {
    G = G2; in = ui; out = uo; n = 256; r = gw - 512;
  }
  const float4* Gr = (const float4*)(G + (size_t)r * n);
  const float4* uv = (const float4*)in;
  float acc = 0.f;
  for (int c = lane; c < (n >> 2); c += 64) {
    float4 g = Gr[c], u = uv[c];
    acc += g.x * u.x + g.y * u.y + g.z * u.z + g.w * u.w;
  }
  for (int off = 32; off; off >>= 1) acc += __shfl_down(acc, off, 64);
  if (lane == 0) out[r] = 0.25f * acc;
}

// ---------------- sigma ----------------------------------------------------
__global__ __launch_bounds__(256) void sigma_kernel(
    const float* __restrict__ vA, const float* __restrict__ vB,
    const float* __restrict__ uA, const float* __restrict__ uB,
    float* __restrict__ sig) {
  float s[4] = {0.f, 0.f, 0.f, 0.f};
  for (int i = threadIdx.x; i < KCAT; i += 256) {
    s[0] += vA[i] * vB[i];
    s[1] += vA[i] * vA[i];
  }
  for (int i = threadIdx.x; i < D_LAT; i += 256) {
    s[2] += uA[i] * uA[i];
    s[3] += uA[i] * uB[i];
  }
  __shared__ float red[4][4];
  int lane = threadIdx.x & 63, w = threadIdx.x >> 6;
  for (int k = 0; k < 4; k++) {
    float a = s[k];
    for (int off = 32; off; off >>= 1) a += __shfl_down(a, off, 64);
    if (lane == 0) red[k][w] = a;
  }
  __syncthreads();
  if (threadIdx.x == 0) {
    float d0 = red[0][0] + red[0][1] + red[0][2] + red[0][3];
    float d1 = red[1][0] + red[1][1] + red[1][2] + red[1][3];
    float d2 = red[2][0] + red[2][1] + red[2][2] + red[2][3];
    float d3 = red[3][0] + red[3][1] + red[3][2] + red[3][3];
    sig[0] = sqrtf(0.25f * d0 / d1);
    sig[1] = sqrtf(0.25f * d2 / d3);
  }
}

// ---------------- fold sigma into bf16 weights -----------------------------
__global__ void wfold_kernel(const float* __restrict__ W1,
                             const float* __restrict__ W2,
                             const float* __restrict__ sig,
                             __hip_bfloat16* __restrict__ W1b,
                             __hip_bfloat16* __restrict__ W2b) {
  int i = blockIdx.x * 256 + threadIdx.x;
  if (i < D_HID * KCAT) W1b[i] = __float2bfloat16(W1[i] * sig[0]);
  int j = i - D_HID * KCAT;
  if (j >= 0 && j < D_LAT * D_HID) W2b[j] = __float2bfloat16(W2[j] * sig[1]);
}

// ---------------- warm-up fusions ------------------------------------------
__global__ void warm1_kernel(const float* __restrict__ Fh,
                             float* __restrict__ Xh,
                             __hip_bfloat16* __restrict__ zc) {
  int i = blockIdx.x * 256 + threadIdx.x;
  float v = Fh[i];
  Xh[SLOT + i] = v;
  zc[(i >> 8) * KCAT + (i & 255)] = __float2bfloat16(v);
}
__global__ void warm2_kernel(const float* __restrict__ Fh,
                             float* __restrict__ Xh, float* __restrict__ Fw) {
  int i = blockIdx.x * 256 + threadIdx.x;
  Xh[2 * SLOT + i] = Fh[i];
  Fw[2 * SLOT + i] = Fh[SLOT + i];
}

// ---------------- bf16 MFMA GEMM: C = tanh(A @ W^T + bias) -----------------
template <int BM, int BN, bool OUT_BF16>
__global__ __launch_bounds__(256) void gemm_mfma(
    const __hip_bfloat16* __restrict__ A, const __hip_bfloat16* __restrict__ W,
    int K, const float* __restrict__ bias, float* __restrict__ Cf,
    __hip_bfloat16* __restrict__ Cb, int N) {
  __shared__ __align__(16) u16 lds[(BM + BN) * 64];
  u16* As = lds;
  u16* Ws = lds + BM * 64;
  const int tid = threadIdx.x;
  const int lane = tid & 63;
  const int wid = tid >> 6;
  const int wy = wid >> 1, wx = wid & 1;
  constexpr int WM = BM / 2, WN = BN / 2;
  constexpr int MB = WM / 16, NB = WN / 16;
  const int bm = blockIdx.x * BM;
  const int bn = blockIdx.y * BN;
  const int rlo = lane & 15, quad = lane >> 4;

  f32x4 acc[MB][NB] = {};

  for (int k0 = 0; k0 < K; k0 += 64) {
    for (int c = tid; c < BM * 8; c += 256) {
      int r = c >> 3, o = (c & 7) ^ (r & 7);
      __builtin_amdgcn_global_load_lds(
          (const __attribute__((address_space(1))) void*)(A + (size_t)(bm + r) * K + k0 + o * 8),
          (__attribute__((address_space(3))) void*)(As + c * 8), 16, 0, 0);
    }
    for (int c = tid; c < BN * 8; c += 256) {
      int r = c >> 3, o = (c & 7) ^ (r & 7);
      __builtin_amdgcn_global_load_lds(
          (const __attribute__((address_space(1))) void*)(W + (size_t)(bn + r) * K + k0 + o * 8),
          (__attribute__((address_space(3))) void*)(Ws + c * 8), 16, 0, 0);
    }
    __syncthreads();
#pragma unroll
    for (int kk = 0; kk < 2; kk++) {
      bf16x8 af[MB], bfr[NB];
#pragma unroll
      for (int mb = 0; mb < MB; mb++) {
        int r = wy * WM + mb * 16 + rlo;
        int o = (kk * 4 + quad) ^ (r & 7);
        af[mb] = *(const bf16x8*)(As + (r * 8 + o) * 8);
      }
#pragma unroll
      for (int nb = 0; nb < NB; nb++) {
        int r = wx * WN + nb * 16 + rlo;
        int o = (kk * 4 + quad) ^ (r & 7);
        bfr[nb] = *(const bf16x8*)(Ws + (r * 8 + o) * 8);
      }
#pragma unroll
      for (int mb = 0; mb < MB; mb++)
#pragma unroll
        for (int nb = 0; nb < NB; nb++)
          acc[mb][nb] = __builtin_amdgcn_mfma_f32_16x16x32_bf16(
              af[mb], bfr[nb], acc[mb][nb], 0, 0, 0);
    }
    __syncthreads();
  }

#pragma unroll
  for (int mb = 0; mb < MB; mb++) {
#pragma unroll
    for (int nb = 0; nb < NB; nb++) {
      int n = bn + wx * WN + nb * 16 + rlo;
      float bv = bias[n];
#pragma unroll
      for (int rg = 0; rg < 4; rg++) {
        int m = bm + wy * WM + mb * 16 + quad * 4 + rg;
        float val = tanhf(acc[mb][nb][rg] + bv);
        if constexpr (OUT_BF16) {
          Cb[(size_t)m * N + n] = __float2bfloat16(val);
        } else {
          Cf[(size_t)m * N + n] = val;
        }
      }
    }
  }
}

// ---------------- Anderson step (wave per batch row, register-resident) ----
// MK compile-time: all loops unroll, dF/dG/vals/A/alpha live in registers
// (round-7 version had runtime mk -> scratch spill, 57MB writes/dispatch).
// Lane owns elements [4l, 4l+4): f32x4 loads (1KB/wave/slot in one instr).
template <int MK>
__global__ __launch_bounds__(256) void anderson_step_kernel(
    const float* __restrict__ Xh, const float* __restrict__ Fh,
    float* __restrict__ Xw, __hip_bfloat16* __restrict__ zc, int t) {
  const int lane = threadIdx.x & 63;
  const int wid = threadIdx.x >> 6;
  const int b = blockIdx.x * 4 + wid;
  const int base = b * D_LAT + 4 * lane;

  const int sl0 = (t - 1) % NRING;
  f32x4 fa = *(const f32x4*)(Fh + (size_t)sl0 * SLOT + base);
  f32x4 xa = *(const f32x4*)(Xh + (size_t)sl0 * SLOT + base);
  const f32x4 Fm1 = fa;
  const f32x4 r = fa - xa;

  f32x4 dF[MK], dG[MK];
#pragma unroll
  for (int i = 1; i <= MK; i++) {
    int s2 = (t - 1 - i) % NRING;
    f32x4 fb = *(const f32x4*)(Fh + (size_t)s2 * SLOT + base);
    f32x4 xb = *(const f32x4*)(Xh + (size_t)s2 * SLOT + base);
    dF[i - 1] = fa - fb;
    dG[i - 1] = dF[i - 1] - (xa - xb);
    fa = fb;
    xa = xb;
  }

  constexpr int NV = MK * (MK + 1) / 2 + MK;
  float vals[NV];
  {
    int p = 0;
#pragma unroll
    for (int i = 0; i < MK; i++)
#pragma unroll
      for (int j = i; j < MK; j++) {
        f32x4 q = dG[i] * dG[j];
        vals[p++] = q[0] + q[1] + q[2] + q[3];
      }
#pragma unroll
    for (int i = 0; i < MK; i++) {
      f32x4 q = dG[i] * r;
      vals[p++] = q[0] + q[1] + q[2] + q[3];
    }
  }
#pragma unroll
  for (int off = 1; off <= 32; off <<= 1)
#pragma unroll
    for (int v = 0; v < NV; v++) vals[v] += __shfl_xor(vals[v], off, 64);

  double A[MK][MK], bv[MK], alpha[MK];
  {
    int p = 0;
#pragma unroll
    for (int i = 0; i < MK; i++)
#pragma unroll
      for (int j = i; j < MK; j++) {
        A[i][j] = (double)vals[p];
        A[j][i] = (double)vals[p];
        p++;
      }
#pragma unroll
    for (int i = 0; i < MK; i++) A[i][i] += (double)1e-4f;
#pragma unroll
    for (int i = 0; i < MK; i++) bv[i] = (double)vals[p++];
  }

#pragma unroll
  for (int c = 0; c < MK; c++) {
    double inv = 1.0 / A[c][c];
#pragma unroll
    for (int rr = c + 1; rr < MK; rr++) {
      double fct = A[rr][c] * inv;
#pragma unroll
      for (int cc = c; cc < MK; cc++) A[rr][cc] -= fct * A[c][cc];
      bv[rr] -= fct * bv[c];
    }
  }
#pragma unroll
  for (int i = MK - 1; i >= 0; i--) {
    double s = bv[i];
#pragma unroll
    for (int j = i + 1; j < MK; j++) s -= A[i][j] * alpha[j];
    alpha[i] = s / A[i][i];
  }

  f32x4 x = Fm1;
#pragma unroll
  for (int i = 0; i < MK; i++) x -= dF[i] * (float)alpha[i];
  *(f32x4*)(Xw + base) = x;
  if (zc != nullptr) {
    union { __hip_bfloat16 h[4]; unsigned long long u; } cv;
#pragma unroll
    for (int j = 0; j < 4; j++) cv.h[j] = __float2bfloat16(x[j]);
    *(unsigned long long*)(zc + (size_t)b * KCAT + 4 * lane) = cv.u;
  }
}

// ---------------- host orchestration ---------------------------------------
static void eval_f(const __hip_bfloat16* zc, const __hip_bfloat16* W1b,
                   const __hip_bfloat16* W2b, const float* b1, const float* b2,
                   __hip_bfloat16* hb, float* Fout, hipStream_t stream) {
  gemm_mfma<64, 64, true><<<dim3(B_ROWS / 64, D_HID / 64), 256, 0, stream>>>(
      zc, W1b, KCAT, b1, nullptr, hb, D_HID);
  gemm_mfma<32, 32, false><<<dim3(B_ROWS / 32, D_LAT / 32), 256, 0, stream>>>(
      hb, W2b, D_HID, b2, Fout, nullptr, D_LAT);
}

extern "C" void kernel_launch(void* const* d_in, const int* in_sizes, int n_in,
                              void* d_out, int out_size, void* d_ws,
                              size_t ws_size, hipStream_t stream) {
  const float* ctx = (const float*)d_in[0];
  const float* W1 = (const float*)d_in[1];
  const float* b1 = (const float*)d_in[2];
  const float* W2 = (const float*)d_in[3];
  const float* b2 = (const float*)d_in[4];
  float* out = (float*)d_out;

  float* ws = (float*)d_ws;
  float* sig = ws;                       // 16
  float* vA = ws + 16;                   // 512
  float* vB = vA + KCAT;                 // 512
  float* uA = vB + KCAT;                 // 256
  float* uB = uA + D_LAT;                // 256
  float* G1p = uB + D_LAT;               // 512*512
  float* G2 = G1p + KCAT * KCAT;         // 256*256
  float* Xh = G2 + D_LAT * D_LAT;        // 7*SLOT
  float* Fh = Xh + NRING * SLOT;         // 7*SLOT
  __hip_bfloat16* W1b = (__hip_bfloat16*)(Fh + NRING * SLOT);  // 524288
  __hip_bfloat16* W2b = W1b + D_HID * KCAT;                    // 262144
  __hip_bfloat16* zc = W2b + D_LAT * D_HID;                    // 2048*512
  __hip_bfloat16* hb = zc + B_ROWS * KCAT;                     // 2048*1024
  // ~38.5 MB total

  init_kernel<<<(B_ROWS * KCAT + 255) / 256, 256, 0, stream>>>(ctx, zc, vA, uA,
                                                               G1p, G2);
  gram_kernel<<<1280, 256, 0, stream>>>(W1, W2, G1p, G2);
  colsum_kernel<<<64, 256, 0, stream>>>(W1, vA);

  for (int it = 1; it <= 21; it++) {
    const float* vi; float* vo;
    const float* ui; float* uo;
    if (it & 1) { vi = vB; vo = vA; ui = uA; uo = uB; }
    else        { vi = vA; vo = vB; ui = uB; uo = uA; }
    pmv_kernel<<<192, 256, 0, stream>>>(G1p, G2, vi, vo, ui, uo, it >= 2);
  }
  sigma_kernel<<<1, 256, 0, stream>>>(vA, vB, uA, uB, sig);
  wfold_kernel<<<(D_HID * KCAT + D_LAT * D_HID + 255) / 256, 256, 0, stream>>>(
      W1, W2, sig, W1b, W2b);

  hipMemsetAsync(Xh, 0, SLOT * sizeof(float), stream);

  eval_f(zc, W1b, W2b, b1, b2, hb, Fh, stream);
  warm1_kernel<<<SLOT / 256, 256, 0, stream>>>(Fh, Xh, zc);
  eval_f(zc, W1b, W2b, b1, b2, hb, Fh + SLOT, stream);
  warm2_kernel<<<SLOT / 256, 256, 0, stream>>>(Fh, Xh, Fh);

  // Anderson loop: t = 3..25
  for (int t = 3; t <= 25; t++) {
    int mk = (t - 1 < 5) ? (t - 1) : 5;
    float* Xw = (t == 25) ? out : (Xh + (t % NRING) * SLOT);
    __hip_bfloat16* zarg = (t == 25) ? nullptr : zc;
    dim3 g(B_ROWS / 4);
    if (mk == 2)
      anderson_step_kernel<2><<<g, 256, 0, stream>>>(Xh, Fh, Xw, zarg, t);
    else if (mk == 3)
      anderson_step_kernel<3><<<g, 256, 0, stream>>>(Xh, Fh, Xw, zarg, t);
    else if (mk == 4)
      anderson_step_kernel<4><<<g, 256, 0, stream>>>(Xh, Fh, Xw, zarg, t);
    else
      anderson_step_kernel<5><<<g, 256, 0, stream>>>(Xh, Fh, Xw, zarg, t);
    if (t < 25) {
      eval_f(zc, W1b, W2b, b1, b2, hb, Fh + (t % NRING) * SLOT, stream);
    }
  }
}